// Round 18
// baseline (464.185 us; speedup 1.0000x reference)
//
#include <hip/hip_runtime.h>
#include <math.h>

#define HID 128

typedef float f32x4 __attribute__((ext_vector_type(4)));
typedef short bf16x8 __attribute__((ext_vector_type(8)));
typedef unsigned int uint32;

__device__ __forceinline__ float leaky02(float z) { return z >= 0.f ? z : 0.2f * z; }
__device__ __forceinline__ unsigned short f2bf(float f) {
  uint32 u = __float_as_uint(f);
  u = (u + 0x7fff + ((u >> 16) & 1)) >> 16;  // RNE
  return (unsigned short)u;
}
__device__ __forceinline__ float bf2f(uint32 us) { return __uint_as_float(us << 16); }
__device__ __forceinline__ float bflo(uint32 w) { return __uint_as_float(w << 16); }
__device__ __forceinline__ float bfhi(uint32 w) { return __uint_as_float(w & 0xffff0000u); }

// ---------------- node encoder: h_bf = relu(concat(feat) @ W_in + b_in) ----------------
__global__ void k_enc(const float* __restrict__ nodenum, const int* __restrict__ c0,
                      const int* __restrict__ c1, const int* __restrict__ batch,
                      const float* __restrict__ recipe,
                      const float* __restrict__ e0, const float* __restrict__ e1,
                      const float* __restrict__ Win, const float* __restrict__ bin,
                      unsigned short* __restrict__ hb, int n) {
  __shared__ float f[8][40];
  __shared__ int idx[8][3];
  int t = threadIdx.x;  // 256
  int col = t & 127;
  int half = t >> 7;
  float w[40];
#pragma unroll
  for (int k = 0; k < 38; k++) w[k] = Win[k * 128 + col];
  w[38] = 0.f;
  w[39] = 0.f;
  float bias = bin[col];
  int ntiles = (n + 7) / 8;
  for (int tile = blockIdx.x; tile < ntiles; tile += gridDim.x) {
    int base = tile * 8;
    if (t < 64) {
      int r = t >> 3, k = t & 7;
      int v = base + r;
      f[r][k] = (v < n) ? nodenum[(size_t)v * 8 + k] : 0.f;
    } else if (t < 88) {
      int j = t - 64;
      int r = j / 3, which = j - r * 3;
      int v = base + r;
      int val = 0;
      if (v < n) val = (which == 0) ? c0[v] : ((which == 1) ? c1[v] : batch[v]);
      idx[r][which] = val;
    } else if (t >= 240) {
      int r = t - 240;
      if (r < 8) { f[r][38] = 0.f; f[r][39] = 0.f; }
    }
    __syncthreads();
    if (t < 240) {
      int r = t / 30, k = t - r * 30;
      float val;
      if (k < 6) val = e0[idx[r][0] * 6 + k];
      else if (k < 14) val = e1[idx[r][1] * 8 + (k - 6)];
      else val = recipe[idx[r][2] * 16 + (k - 14)];
      f[r][8 + k] = val;
    }
    __syncthreads();
#pragma unroll
    for (int rr = 0; rr < 4; rr++) {
      int r = half * 4 + rr;
      int v = base + r;
      float acc = bias;
#pragma unroll
      for (int k4 = 0; k4 < 10; k4++) {
        float4 fv = *(const float4*)(&f[r][k4 * 4]);
        acc += fv.x * w[k4 * 4] + fv.y * w[k4 * 4 + 1] + fv.z * w[k4 * 4 + 2] +
               fv.w * w[k4 * 4 + 3];
      }
      if (v < n) hb[(size_t)v * 128 + col] = f2bf(fmaxf(acc, 0.f));
    }
    __syncthreads();
  }
}

// ---- parallel precompute P_l (18x4), q_l (4); one block per layer ----
__global__ void k_prep(const float* __restrict__ gle, const float* __restrict__ atte,
                       const float* __restrict__ We, const float* __restrict__ be,
                       float* __restrict__ P, float* __restrict__ q) {
  __shared__ float M[512];  // [k][hh]
  int l = blockIdx.x;
  int t = threadIdx.x;  // 256
#pragma unroll
  for (int i = 0; i < 2; i++) {
    int idx = t + i * 256;
    int k = idx >> 2, hh = idx & 3;
    float acc = 0.f;
    for (int c = 0; c < 32; c++)
      acc += gle[l * 16384 + k * 128 + hh * 32 + c] * atte[l * 128 + hh * 32 + c];
    M[k * 4 + hh] = acc;
  }
  __syncthreads();
  if (t < 72) {
    int j = t >> 2, hh = t & 3;
    float acc = 0.f;
    for (int k = 0; k < 128; k++) acc += We[j * 128 + k] * M[k * 4 + hh];
    P[(l * 18 + j) * 4 + hh] = acc;
  } else if (t < 76) {
    int hh = t - 72;
    float acc = 0.f;
    for (int k = 0; k < 128; k++) acc += be[k] * M[k * 4 + hh];
    q[l * 4 + hh] = acc;
  }
}

// ---- precompute WbfT[l][col][k] = bf16(gat_lin[l][k][col]) ----
__global__ void k_wprep(const float* __restrict__ glin, unsigned short* __restrict__ WbfT) {
  int idx = blockIdx.x * 256 + threadIdx.x;
  if (idx >= 3 * 128 * 128) return;
  int l = idx >> 14;
  int rem = idx & 16383;
  int col = rem >> 7;
  int k = rem & 127;
  WbfT[idx] = f2bf(glin[(l << 14) + k * 128 + col]);
}

// ---------------- degree histogram ----------------
__global__ void k_deg(const int* __restrict__ dst, int* __restrict__ cnt, int E) {
  int i = blockIdx.x * 256 + threadIdx.x;
  if (i < E) atomicAdd(&cnt[dst[i]], 1);
}

// ------- per-edge a_e (all 3 layers) written DIRECTLY in CSR order via cursor atomics -------
__global__ void k_ae(const float* __restrict__ enum_, const int* __restrict__ ec0,
                     const int* __restrict__ ec1, const int* __restrict__ dst,
                     const int* __restrict__ srcarr,
                     const float* __restrict__ ee0, const float* __restrict__ ee1,
                     const float* __restrict__ P, const float* __restrict__ q,
                     int* __restrict__ cursor, float* __restrict__ ae3,
                     int* __restrict__ srcc, int E) {
  __shared__ float Ps[216];
  __shared__ float qs[12];
  int t = threadIdx.x;
  for (int i = t; i < 216; i += 256) Ps[i] = P[i];
  if (t < 12) qs[t] = q[t];
  __syncthreads();
  int i = blockIdx.x * 256 + t;
  if (i >= E) return;
  float raw[18];
  float4 nm = *(const float4*)(enum_ + (size_t)i * 4);
  raw[0] = nm.x; raw[1] = nm.y; raw[2] = nm.z; raw[3] = nm.w;
  int a0 = ec0[i], a1 = ec1[i];
  float4 eb0 = *(const float4*)(ee0 + a0 * 4);
  raw[4] = eb0.x; raw[5] = eb0.y; raw[6] = eb0.z; raw[7] = eb0.w;
#pragma unroll
  for (int j = 0; j < 10; j++) raw[8 + j] = ee1[a1 * 10 + j];
  int d = dst[i];
  int pos = atomicAdd(&cursor[d], 1);
  srcc[pos] = srcarr[i];
#pragma unroll
  for (int l = 0; l < 3; l++) {
    float o[4];
#pragma unroll
    for (int hh = 0; hh < 4; hh++) {
      float acc = qs[l * 4 + hh];
#pragma unroll
      for (int j = 0; j < 18; j++) acc += raw[j] * Ps[(l * 18 + j) * 4 + hh];
      o[hh] = acc;
    }
    *(float4*)(ae3 + ((size_t)l * E + pos) * 4) = make_float4(o[0], o[1], o[2], o[3]);
  }
}

// ---- node-parallel self-loop means from CSR-ordered ae3; aeL layer-major [l][v][4] ----
__global__ void k_loopmean(const float* __restrict__ ae3, const int* __restrict__ rowptr,
                           float* __restrict__ aeL, int n, int E) {
  int v = blockIdx.x * 256 + threadIdx.x;
  if (v >= n) return;
  int beg = rowptr[v], end = rowptr[v + 1];
  float inv = (end > beg) ? 1.f / (float)(end - beg) : 0.f;
#pragma unroll
  for (int l = 0; l < 3; l++) {
    float4 s = make_float4(0.f, 0.f, 0.f, 0.f);
    const float4* base = (const float4*)(ae3 + (size_t)l * E * 4);
    for (int j = beg; j < end; j++) {
      float4 a = base[j];
      s.x += a.x; s.y += a.y; s.z += a.z; s.w += a.w;
    }
    *(float4*)(aeL + ((size_t)l * n + v) * 4) =
        make_float4(s.x * inv, s.y * inv, s.z * inv, s.w * inv);
  }
}

// ---------------- CSR build: exclusive scan of cnt -> rowptr (cursor = copy) ----------------
__global__ void k_scan1(const int* __restrict__ cnt, int* __restrict__ excl,
                        int* __restrict__ bsum, int n) {
  __shared__ int sh[256];
  int t = threadIdx.x;
  int i = blockIdx.x * 256 + t;
  int v = (i < n) ? cnt[i] : 0;
  sh[t] = v;
  __syncthreads();
  for (int off = 1; off < 256; off <<= 1) {
    int add = (t >= off) ? sh[t - off] : 0;
    __syncthreads();
    sh[t] += add;
    __syncthreads();
  }
  if (i < n) excl[i] = sh[t] - v;
  if (t == 255) bsum[blockIdx.x] = sh[255];
}

__global__ void k_scan2(int* __restrict__ bsum, int nb) {
  __shared__ int sh[512];
  int t = threadIdx.x;
  int v = (t < nb) ? bsum[t] : 0;
  sh[t] = v;
  __syncthreads();
  for (int off = 1; off < 512; off <<= 1) {
    int add = (t >= off) ? sh[t - off] : 0;
    __syncthreads();
    sh[t] += add;
    __syncthreads();
  }
  if (t < nb) bsum[t] = sh[t] - v;
}

__global__ void k_scan3(int* __restrict__ rowptr, const int* __restrict__ boff,
                        int* __restrict__ cursor, int n, int E) {
  int i = blockIdx.x * 256 + threadIdx.x;
  if (i < n) {
    int val = rowptr[i] + boff[i >> 8];
    rowptr[i] = val;
    cursor[i] = val;
  }
  if (i == 0) rowptr[n] = E;
}

// ------- x = h @ gat_lin[l] via bf16 MFMA; NO LDS, NO barriers: A-fragments direct from global -------
// 8 waves/block: wave w -> rows tile*64 + (w&3)*16, col half w>>2. A-frag: 16B at
// h[row*128 + ks*32 + lg*8] (64-B segments per lg-quad, L1-shared across the block's waves).
__global__ void __launch_bounds__(512, 4)
k_x(const unsigned short* __restrict__ hb, const unsigned short* __restrict__ WbfT,
    unsigned short* __restrict__ xb, int n) {
  int t = threadIdx.x;  // 512
  int w = t >> 6, l = t & 63;
  int ch = w >> 2, wr = w & 3;
  int lr = l & 15, lg = l >> 4;
  bf16x8 bfrag[4][4];
#pragma unroll
  for (int ct = 0; ct < 4; ct++) {
#pragma unroll
    for (int ks = 0; ks < 4; ks++) {
      int col = ch * 64 + ct * 16 + lr;
      int k0 = ks * 32 + lg * 8;
      bfrag[ct][ks] = *(const bf16x8*)(WbfT + col * 128 + k0);
    }
  }
  int ntiles = (n + 63) >> 6;
  for (int tile = blockIdx.x; tile < ntiles; tile += gridDim.x) {
    int rowA = tile * 64 + wr * 16 + lr;
    int rowL = min(rowA, n - 1);
    f32x4 acc[4];
#pragma unroll
    for (int ct = 0; ct < 4; ct++) acc[ct] = (f32x4){0.f, 0.f, 0.f, 0.f};
#pragma unroll
    for (int ks = 0; ks < 4; ks++) {
      bf16x8 a = *(const bf16x8*)(hb + (size_t)rowL * 128 + ks * 32 + lg * 8);
#pragma unroll
      for (int ct = 0; ct < 4; ct++)
        acc[ct] = __builtin_amdgcn_mfma_f32_16x16x32_bf16(a, bfrag[ct][ks], acc[ct], 0, 0, 0);
    }
#pragma unroll
    for (int j = 0; j < 4; j++) {
      int row = tile * 64 + wr * 16 + lg * 4 + j;
      if (row < n) {
#pragma unroll
        for (int ct = 0; ct < 4; ct++)
          xb[(size_t)row * 128 + ch * 64 + ct * 16 + lr] = f2bf(acc[ct][j]);
      }
    }
  }
}

// ---- a_s/a_d from x: coalesced row read, 16-lane per-head shuffle reduce ----
__global__ void k_att(const unsigned short* __restrict__ xb, const float* __restrict__ att_s,
                      const float* __restrict__ att_d, float* __restrict__ a_s,
                      float* __restrict__ a_d, int n) {
  int t = threadIdx.x;  // 256
  int wid = t >> 6, lane = t & 63;
  int head = lane >> 4;
  float as0 = att_s[lane * 2], as1 = att_s[lane * 2 + 1];
  float ad0 = att_d[lane * 2], ad1 = att_d[lane * 2 + 1];
  for (int v = blockIdx.x * 4 + wid; v < n; v += gridDim.x * 4) {
    uint32 xw = *(const uint32*)(xb + (size_t)v * 128 + lane * 2);
    float x0 = bflo(xw), x1 = bfhi(xw);
    float ps = x0 * as0 + x1 * as1;
    float pd = x0 * ad0 + x1 * ad1;
    ps += __shfl_xor(ps, 1); pd += __shfl_xor(pd, 1);
    ps += __shfl_xor(ps, 2); pd += __shfl_xor(pd, 2);
    ps += __shfl_xor(ps, 4); pd += __shfl_xor(pd, 4);
    ps += __shfl_xor(ps, 8); pd += __shfl_xor(pd, 8);
    if ((lane & 15) == 0) {
      a_s[(size_t)v * 4 + head] = ps;
      a_d[(size_t)v * 4 + head] = pd;
    }
  }
}

// -------- per-dst softmax: shfl-light online reduction + 2x-unrolled packed bf16 gather --------
// (round-12 structure — best measured at 56.1 µs)
__global__ void k_agg(const unsigned short* __restrict__ xb, const float* __restrict__ a_s,
                      const float* __restrict__ a_d, const float* __restrict__ ae3,
                      const float* __restrict__ aeL,
                      const int* __restrict__ rowptr, const int* __restrict__ srcc,
                      const float* __restrict__ bias,
                      unsigned short* __restrict__ hbout, int n, int E, int l) {
  int wid = threadIdx.x >> 6;
  int v = blockIdx.x * 4 + wid;
  if (v >= n) return;
  int lane = threadIdx.x & 63;
  int el = lane >> 2;
  int hh = lane & 3;
  float ad_own = a_d[(size_t)v * 4 + hh];
  float as_own = a_s[(size_t)v * 4 + hh];
  float aeL_own = aeL[((size_t)l * n + v) * 4 + hh];
  float m_own = leaky02(as_own + ad_own + aeL_own);
  float s_own = 1.f;  // self contributes exp(0)
  int c2 = lane * 2;
  int headO = lane >> 4;
  const char* xB = (const char*)xb;
  uint32 coff = (uint32)c2 * 2u;
  uint32 wv = *(const uint32*)(xB + ((uint32)v << 8) + coff);
  float a0 = bflo(wv);
  float a1 = bfhi(wv);
  int beg = rowptr[v], end = rowptr[v + 1];
  const float* aeB = ae3 + (size_t)l * E * 4;
  for (int cb = beg; cb < end; cb += 16) {
    int ne = end - cb;
    if (ne > 16) ne = 16;
    float logit = -1e30f;
    int srcE = 0;
    if (el < ne) {
      int j = cb + el;
      srcE = srcc[j];
      float asrc = a_s[(size_t)srcE * 4 + hh];
      float aev = aeB[(size_t)j * 4 + hh];
      logit = leaky02(asrc + ad_own + aev);
    }
    float cm = logit;
    cm = fmaxf(cm, __shfl_xor(cm, 4));
    cm = fmaxf(cm, __shfl_xor(cm, 8));
    cm = fmaxf(cm, __shfl_xor(cm, 16));
    cm = fmaxf(cm, __shfl_xor(cm, 32));
    float mn_own = fmaxf(m_own, cm);
    float p = (el < ne) ? __expf(logit - mn_own) : 0.f;
    float ps = p;
    ps += __shfl_xor(ps, 4);
    ps += __shfl_xor(ps, 8);
    ps += __shfl_xor(ps, 16);
    ps += __shfl_xor(ps, 32);
    float c_own = __expf(m_own - mn_own);
    m_own = mn_own;
    s_own = s_own * c_own + ps;
    float cO = __shfl(c_own, headO);
    a0 *= cO;
    a1 *= cO;
    int e = 0;
    for (; e + 2 <= ne; e += 2) {
      int se0 = __builtin_amdgcn_readlane(srcE, e * 4);
      int se1 = __builtin_amdgcn_readlane(srcE, e * 4 + 4);
      float p0 = __shfl(p, e * 4 + headO);
      float p1 = __shfl(p, e * 4 + 4 + headO);
      uint32 x0 = *(const uint32*)(xB + ((uint32)se0 << 8) + coff);
      uint32 x1 = *(const uint32*)(xB + ((uint32)se1 << 8) + coff);
      a0 += p0 * bflo(x0) + p1 * bflo(x1);
      a1 += p0 * bfhi(x0) + p1 * bfhi(x1);
    }
    if (e < ne) {
      int se = __builtin_amdgcn_readlane(srcE, e * 4);
      float pC = __shfl(p, e * 4 + headO);
      uint32 xw = *(const uint32*)(xB + ((uint32)se << 8) + coff);
      a0 += pC * bflo(xw);
      a1 += pC * bfhi(xw);
    }
  }
  float sO = __shfl(s_own, headO);
  float r0 = fmaxf(a0 / sO + bias[l * HID + c2], 0.f);
  float r1 = fmaxf(a1 / sO + bias[l * HID + c2 + 1], 0.f);
  uint32 pk = (uint32)f2bf(r0) | ((uint32)f2bf(r1) << 16);
  *(uint32*)(hbout + (size_t)v * HID + c2) = pk;
}

// ---------------- pooling over bf16 h: batch sorted -> register accumulate ----------------
__global__ void k_pool(const unsigned short* __restrict__ hb, const int* __restrict__ batch,
                       float* __restrict__ g, int n) {
  int t = threadIdx.x;  // 128
  int per = (n + gridDim.x - 1) / gridDim.x;
  int start = blockIdx.x * per;
  int end = min(n, start + per);
  float acc = 0.f;
  int cur = -1;
  for (int v = start; v < end; v++) {
    int b = batch[v];
    if (b != cur) {
      if (cur >= 0) atomicAdd(&g[cur * 128 + t], acc);
      acc = 0.f;
      cur = b;
    }
    acc += bf2f((uint32)hb[(size_t)v * 128 + t]);
  }
  if (cur >= 0) atomicAdd(&g[cur * 128 + t], acc);
}

// ---------------- head MLP: one block per graph, LDS tree reduce ----------------
__global__ void k_head(const float* __restrict__ g, const float* __restrict__ Wr1,
                       const float* __restrict__ br1, const float* __restrict__ Wr2,
                       const float* __restrict__ br2, float* __restrict__ out, int G_) {
  __shared__ float gl[128];
  __shared__ float red[128];
  int i = blockIdx.x;
  int t = threadIdx.x;  // 128
  gl[t] = g[i * 128 + t];
  __syncthreads();
  float acc = br1[t];
  for (int k = 0; k < 128; k++) acc += gl[k] * Wr1[k * 128 + t];
  float hv = fmaxf(acc, 0.f);
  red[t] = hv * Wr2[t];
  __syncthreads();
  for (int off = 64; off >= 1; off >>= 1) {
    if (t < off) red[t] += red[t + off];
    __syncthreads();
  }
  if (t == 0) out[i] = red[0] + br2[0];
}

extern "C" void kernel_launch(void* const* d_in, const int* in_sizes, int n_in,
                              void* d_out, int out_size, void* d_ws, size_t ws_size,
                              hipStream_t stream) {
  const float* node_numeric = (const float*)d_in[0];
  const int* node_cat0 = (const int*)d_in[1];
  const int* node_cat1 = (const int*)d_in[2];
  const float* edge_numeric = (const float*)d_in[3];
  const int* edge_cat0 = (const int*)d_in[4];
  const int* edge_cat1 = (const int*)d_in[5];
  const int* edge_index = (const int*)d_in[6];
  const int* batch = (const int*)d_in[7];
  const float* recipe = (const float*)d_in[8];
  const float* emb_node0 = (const float*)d_in[9];
  const float* emb_node1 = (const float*)d_in[10];
  const float* emb_edge0 = (const float*)d_in[11];
  const float* emb_edge1 = (const float*)d_in[12];
  const float* W_in = (const float*)d_in[13];
  const float* b_in = (const float*)d_in[14];
  const float* W_edge = (const float*)d_in[15];
  const float* b_edge = (const float*)d_in[16];
  const float* gat_lin = (const float*)d_in[17];
  const float* gat_lin_edge = (const float*)d_in[18];
  const float* att_src = (const float*)d_in[19];
  const float* att_dst = (const float*)d_in[20];
  const float* att_edge = (const float*)d_in[21];
  const float* gat_bias = (const float*)d_in[22];
  const float* W_r1 = (const float*)d_in[23];
  const float* b_r1 = (const float*)d_in[24];
  const float* W_r2 = (const float*)d_in[25];
  const float* b_r2 = (const float*)d_in[26];

  int N = in_sizes[0] / 8;
  int E = in_sizes[3] / 4;
  int Gn = in_sizes[8] / 16;
  const int* srcArr = edge_index;
  const int* dstArr = edge_index + E;

  char* ws = (char*)d_ws;
  size_t o = 0;
  auto alloc = [&](size_t b) {
    char* p = ws + o;
    o = (o + b + 255) & ~(size_t)255;
    return p;
  };
  unsigned short* hbf = (unsigned short*)alloc((size_t)N * 128 * 2);
  unsigned short* xbf = (unsigned short*)alloc((size_t)N * 128 * 2);
  float* ae3 = (float*)alloc((size_t)E * 12 * 4);   // CSR-ordered, layer-major
  float* aeL = (float*)alloc((size_t)N * 12 * 4);   // layer-major [3][N][4]
  float* a_s = (float*)alloc((size_t)N * 4 * 4);
  float* a_d = (float*)alloc((size_t)N * 4 * 4);
  float* P = (float*)alloc(216 * 4);
  float* q = (float*)alloc(12 * 4);
  unsigned short* WbfT = (unsigned short*)alloc(3 * 128 * 128 * 2);
  int* cnt = (int*)alloc((size_t)N * 4);
  int* rowptr = (int*)alloc((size_t)(N + 1) * 4);
  int* cursor = (int*)alloc((size_t)N * 4);
  int* bsum = (int*)alloc(512 * 4);
  int* srcc = (int*)alloc((size_t)E * 4);
  float* g = (float*)alloc((size_t)Gn * 128 * 4);
  (void)ws_size;

  (void)hipMemsetAsync(cnt, 0, (size_t)N * 4, stream);
  (void)hipMemsetAsync(g, 0, (size_t)Gn * 128 * 4, stream);

  int nbl = (N + 255) / 256;
  int ebl = (E + 255) / 256;

  k_enc<<<2048, 256, 0, stream>>>(node_numeric, node_cat0, node_cat1, batch, recipe,
                                  emb_node0, emb_node1, W_in, b_in, hbf, N);
  k_prep<<<3, 256, 0, stream>>>(gat_lin_edge, att_edge, W_edge, b_edge, P, q);
  k_wprep<<<192, 256, 0, stream>>>(gat_lin, WbfT);
  k_deg<<<ebl, 256, 0, stream>>>(dstArr, cnt, E);
  k_scan1<<<nbl, 256, 0, stream>>>(cnt, rowptr, bsum, N);
  k_scan2<<<1, 512, 0, stream>>>(bsum, nbl);
  k_scan3<<<nbl, 256, 0, stream>>>(rowptr, bsum, cursor, N, E);
  k_ae<<<ebl, 256, 0, stream>>>(edge_numeric, edge_cat0, edge_cat1, dstArr, srcArr,
                                emb_edge0, emb_edge1, P, q, cursor, ae3, srcc, E);
  k_loopmean<<<nbl, 256, 0, stream>>>(ae3, rowptr, aeL, N, E);

  for (int l = 0; l < 3; l++) {
    k_x<<<1024, 512, 0, stream>>>(hbf, WbfT + l * 16384, xbf, N);
    k_att<<<2048, 256, 0, stream>>>(xbf, att_src + l * 128, att_dst + l * 128,
                                    a_s, a_d, N);
    k_agg<<<(N + 3) / 4, 256, 0, stream>>>(xbf, a_s, a_d, ae3, aeL, rowptr, srcc,
                                           gat_bias, hbf, N, E, l);
  }
  k_pool<<<1024, 128, 0, stream>>>(hbf, batch, g, N);
  k_head<<<Gn, 128, 0, stream>>>(g, W_r1, b_r1, W_r2, b_r2, (float*)d_out, Gn);
}

// Round 19
// 419.096 us; speedup vs baseline: 1.1076x; 1.1076x over previous
//
#include <hip/hip_runtime.h>
#include <math.h>

#define HID 128

typedef float f32x4 __attribute__((ext_vector_type(4)));
typedef short bf16x8 __attribute__((ext_vector_type(8)));
typedef unsigned int uint32;

__device__ __forceinline__ float leaky02(float z) { return z >= 0.f ? z : 0.2f * z; }
__device__ __forceinline__ unsigned short f2bf(float f) {
  uint32 u = __float_as_uint(f);
  u = (u + 0x7fff + ((u >> 16) & 1)) >> 16;  // RNE
  return (unsigned short)u;
}
__device__ __forceinline__ float bf2f(uint32 us) { return __uint_as_float(us << 16); }
__device__ __forceinline__ float bflo(uint32 w) { return __uint_as_float(w << 16); }
__device__ __forceinline__ float bfhi(uint32 w) { return __uint_as_float(w & 0xffff0000u); }

// ---------------- node encoder: h_bf = relu(concat(feat) @ W_in + b_in) ----------------
__global__ void k_enc(const float* __restrict__ nodenum, const int* __restrict__ c0,
                      const int* __restrict__ c1, const int* __restrict__ batch,
                      const float* __restrict__ recipe,
                      const float* __restrict__ e0, const float* __restrict__ e1,
                      const float* __restrict__ Win, const float* __restrict__ bin,
                      unsigned short* __restrict__ hb, int n) {
  __shared__ float f[8][40];
  __shared__ int idx[8][3];
  int t = threadIdx.x;  // 256
  int col = t & 127;
  int half = t >> 7;
  float w[40];
#pragma unroll
  for (int k = 0; k < 38; k++) w[k] = Win[k * 128 + col];
  w[38] = 0.f;
  w[39] = 0.f;
  float bias = bin[col];
  int ntiles = (n + 7) / 8;
  for (int tile = blockIdx.x; tile < ntiles; tile += gridDim.x) {
    int base = tile * 8;
    if (t < 64) {
      int r = t >> 3, k = t & 7;
      int v = base + r;
      f[r][k] = (v < n) ? nodenum[(size_t)v * 8 + k] : 0.f;
    } else if (t < 88) {
      int j = t - 64;
      int r = j / 3, which = j - r * 3;
      int v = base + r;
      int val = 0;
      if (v < n) val = (which == 0) ? c0[v] : ((which == 1) ? c1[v] : batch[v]);
      idx[r][which] = val;
    } else if (t >= 240) {
      int r = t - 240;
      if (r < 8) { f[r][38] = 0.f; f[r][39] = 0.f; }
    }
    __syncthreads();
    if (t < 240) {
      int r = t / 30, k = t - r * 30;
      float val;
      if (k < 6) val = e0[idx[r][0] * 6 + k];
      else if (k < 14) val = e1[idx[r][1] * 8 + (k - 6)];
      else val = recipe[idx[r][2] * 16 + (k - 14)];
      f[r][8 + k] = val;
    }
    __syncthreads();
#pragma unroll
    for (int rr = 0; rr < 4; rr++) {
      int r = half * 4 + rr;
      int v = base + r;
      float acc = bias;
#pragma unroll
      for (int k4 = 0; k4 < 10; k4++) {
        float4 fv = *(const float4*)(&f[r][k4 * 4]);
        acc += fv.x * w[k4 * 4] + fv.y * w[k4 * 4 + 1] + fv.z * w[k4 * 4 + 2] +
               fv.w * w[k4 * 4 + 3];
      }
      if (v < n) hb[(size_t)v * 128 + col] = f2bf(fmaxf(acc, 0.f));
    }
    __syncthreads();
  }
}

// ---- parallel precompute P_l (18x4), q_l (4); one block per layer ----
__global__ void k_prep(const float* __restrict__ gle, const float* __restrict__ atte,
                       const float* __restrict__ We, const float* __restrict__ be,
                       float* __restrict__ P, float* __restrict__ q) {
  __shared__ float M[512];  // [k][hh]
  int l = blockIdx.x;
  int t = threadIdx.x;  // 256
#pragma unroll
  for (int i = 0; i < 2; i++) {
    int idx = t + i * 256;
    int k = idx >> 2, hh = idx & 3;
    float acc = 0.f;
    for (int c = 0; c < 32; c++)
      acc += gle[l * 16384 + k * 128 + hh * 32 + c] * atte[l * 128 + hh * 32 + c];
    M[k * 4 + hh] = acc;
  }
  __syncthreads();
  if (t < 72) {
    int j = t >> 2, hh = t & 3;
    float acc = 0.f;
    for (int k = 0; k < 128; k++) acc += We[j * 128 + k] * M[k * 4 + hh];
    P[(l * 18 + j) * 4 + hh] = acc;
  } else if (t < 76) {
    int hh = t - 72;
    float acc = 0.f;
    for (int k = 0; k < 128; k++) acc += be[k] * M[k * 4 + hh];
    q[l * 4 + hh] = acc;
  }
}

// ---- precompute WbfT[l][col][k] = bf16(gat_lin[l][k][col]) ----
__global__ void k_wprep(const float* __restrict__ glin, unsigned short* __restrict__ WbfT) {
  int idx = blockIdx.x * 256 + threadIdx.x;
  if (idx >= 3 * 128 * 128) return;
  int l = idx >> 14;
  int rem = idx & 16383;
  int col = rem >> 7;
  int k = rem & 127;
  WbfT[idx] = f2bf(glin[(l << 14) + k * 128 + col]);
}

// ---------------- degree histogram ----------------
__global__ void k_deg(const int* __restrict__ dst, int* __restrict__ cnt, int E) {
  int i = blockIdx.x * 256 + threadIdx.x;
  if (i < E) atomicAdd(&cnt[dst[i]], 1);
}

// ------- per-edge record (32B): 12 bf16 logits (3 layers x 4 heads) + src int + pad -------
// written DIRECTLY in CSR order via cursor atomics: exactly one 32B-aligned store region.
__global__ void k_ae(const float* __restrict__ enum_, const int* __restrict__ ec0,
                     const int* __restrict__ ec1, const int* __restrict__ dst,
                     const int* __restrict__ srcarr,
                     const float* __restrict__ ee0, const float* __restrict__ ee1,
                     const float* __restrict__ P, const float* __restrict__ q,
                     int* __restrict__ cursor, unsigned short* __restrict__ rec,
                     int E) {
  __shared__ float Ps[216];
  __shared__ float qs[12];
  int t = threadIdx.x;
  for (int i = t; i < 216; i += 256) Ps[i] = P[i];
  if (t < 12) qs[t] = q[t];
  __syncthreads();
  int i = blockIdx.x * 256 + t;
  if (i >= E) return;
  float raw[18];
  float4 nm = *(const float4*)(enum_ + (size_t)i * 4);
  raw[0] = nm.x; raw[1] = nm.y; raw[2] = nm.z; raw[3] = nm.w;
  int a0 = ec0[i], a1 = ec1[i];
  float4 eb0 = *(const float4*)(ee0 + a0 * 4);
  raw[4] = eb0.x; raw[5] = eb0.y; raw[6] = eb0.z; raw[7] = eb0.w;
#pragma unroll
  for (int j = 0; j < 10; j++) raw[8 + j] = ee1[a1 * 10 + j];
  int d = dst[i];
  int pos = atomicAdd(&cursor[d], 1);
  uint32 wbuf[8];
#pragma unroll
  for (int l = 0; l < 3; l++) {
    float o[4];
#pragma unroll
    for (int hh = 0; hh < 4; hh++) {
      float acc = qs[l * 4 + hh];
#pragma unroll
      for (int j = 0; j < 18; j++) acc += raw[j] * Ps[(l * 18 + j) * 4 + hh];
      o[hh] = acc;
    }
    wbuf[l * 2] = (uint32)f2bf(o[0]) | ((uint32)f2bf(o[1]) << 16);
    wbuf[l * 2 + 1] = (uint32)f2bf(o[2]) | ((uint32)f2bf(o[3]) << 16);
  }
  wbuf[6] = (uint32)srcarr[i];
  wbuf[7] = 0;
  uint4* dp = (uint4*)(rec + (size_t)pos * 16);
  dp[0] = make_uint4(wbuf[0], wbuf[1], wbuf[2], wbuf[3]);
  dp[1] = make_uint4(wbuf[4], wbuf[5], wbuf[6], wbuf[7]);
}

// ---- node-parallel self-loop means from records; aeL layer-major [l][v][4] f32 ----
__global__ void k_loopmean(const unsigned short* __restrict__ rec,
                           const int* __restrict__ rowptr,
                           float* __restrict__ aeL, int n, int E) {
  int v = blockIdx.x * 256 + threadIdx.x;
  if (v >= n) return;
  int beg = rowptr[v], end = rowptr[v + 1];
  float s[12];
#pragma unroll
  for (int m = 0; m < 12; m++) s[m] = 0.f;
  for (int j = beg; j < end; j++) {
    const uint4* rp = (const uint4*)(rec + (size_t)j * 16);
    uint4 r0 = rp[0];
    uint32 w4 = ((const uint32*)&rp[1])[0];
    uint32 w5 = ((const uint32*)&rp[1])[1];
    s[0] += bflo(r0.x); s[1] += bfhi(r0.x);
    s[2] += bflo(r0.y); s[3] += bfhi(r0.y);
    s[4] += bflo(r0.z); s[5] += bfhi(r0.z);
    s[6] += bflo(r0.w); s[7] += bfhi(r0.w);
    s[8] += bflo(w4);   s[9] += bfhi(w4);
    s[10] += bflo(w5);  s[11] += bfhi(w5);
  }
  float inv = (end > beg) ? 1.f / (float)(end - beg) : 0.f;
#pragma unroll
  for (int l = 0; l < 3; l++)
    *(float4*)(aeL + ((size_t)l * n + v) * 4) =
        make_float4(s[l * 4] * inv, s[l * 4 + 1] * inv, s[l * 4 + 2] * inv,
                    s[l * 4 + 3] * inv);
}

// ---------------- CSR build: exclusive scan of cnt -> rowptr (cursor = copy) ----------------
__global__ void k_scan1(const int* __restrict__ cnt, int* __restrict__ excl,
                        int* __restrict__ bsum, int n) {
  __shared__ int sh[256];
  int t = threadIdx.x;
  int i = blockIdx.x * 256 + t;
  int v = (i < n) ? cnt[i] : 0;
  sh[t] = v;
  __syncthreads();
  for (int off = 1; off < 256; off <<= 1) {
    int add = (t >= off) ? sh[t - off] : 0;
    __syncthreads();
    sh[t] += add;
    __syncthreads();
  }
  if (i < n) excl[i] = sh[t] - v;
  if (t == 255) bsum[blockIdx.x] = sh[255];
}

__global__ void k_scan2(int* __restrict__ bsum, int nb) {
  __shared__ int sh[512];
  int t = threadIdx.x;
  int v = (t < nb) ? bsum[t] : 0;
  sh[t] = v;
  __syncthreads();
  for (int off = 1; off < 512; off <<= 1) {
    int add = (t >= off) ? sh[t - off] : 0;
    __syncthreads();
    sh[t] += add;
    __syncthreads();
  }
  if (t < nb) bsum[t] = sh[t] - v;
}

__global__ void k_scan3(int* __restrict__ rowptr, const int* __restrict__ boff,
                        int* __restrict__ cursor, int n, int E) {
  int i = blockIdx.x * 256 + threadIdx.x;
  if (i < n) {
    int val = rowptr[i] + boff[i >> 8];
    rowptr[i] = val;
    cursor[i] = val;
  }
  if (i == 0) rowptr[n] = E;
}

// ------- x = h @ gat_lin[l] via bf16 MFMA; LDS-staged h; fused a_s/a_d epilogue -------
__global__ void __launch_bounds__(512, 4)
k_x(const unsigned short* __restrict__ hb, const unsigned short* __restrict__ WbfT,
    const float* __restrict__ att_s, const float* __restrict__ att_d,
    unsigned short* __restrict__ xb, float* __restrict__ a_s,
    float* __restrict__ a_d, int n) {
  __shared__ unsigned short hs[64 * 128];
  int t = threadIdx.x;  // 512
  int w = t >> 6, l = t & 63;
  int ch = w >> 2, wr = w & 3;
  int lr = l & 15, lg = l >> 4;
  bf16x8 bfrag[4][4];
#pragma unroll
  for (int ct = 0; ct < 4; ct++) {
#pragma unroll
    for (int ks = 0; ks < 4; ks++) {
      int col = ch * 64 + ct * 16 + lr;
      int k0 = ks * 32 + lg * 8;
      bfrag[ct][ks] = *(const bf16x8*)(WbfT + col * 128 + k0);
    }
  }
  float avs[4], avd[4];
#pragma unroll
  for (int ct = 0; ct < 4; ct++) {
    avs[ct] = att_s[ch * 64 + ct * 16 + lr];
    avd[ct] = att_d[ch * 64 + ct * 16 + lr];
  }
  for (int tb = blockIdx.x * 64; tb < n; tb += gridDim.x * 64) {
    __syncthreads();
#pragma unroll
    for (int i = 0; i < 2; i++) {
      int idx = t + i * 512;
      int r = idx >> 4, c = idx & 15;
      uint4 vv = make_uint4(0, 0, 0, 0);
      if (tb + r < n) vv = *(const uint4*)(hb + (size_t)(tb + r) * 128 + c * 8);
      *(uint4*)(&hs[r * 128 + ((c ^ (r & 7)) * 8)]) = vv;
    }
    __syncthreads();
    f32x4 acc[4];
#pragma unroll
    for (int ct = 0; ct < 4; ct++) acc[ct] = (f32x4){0.f, 0.f, 0.f, 0.f};
#pragma unroll
    for (int ks = 0; ks < 4; ks++) {
      int r = wr * 16 + lr;
      int c = ks * 4 + lg;
      bf16x8 a = *(const bf16x8*)(&hs[r * 128 + ((c ^ (r & 7)) * 8)]);
#pragma unroll
      for (int ct = 0; ct < 4; ct++)
        acc[ct] = __builtin_amdgcn_mfma_f32_16x16x32_bf16(a, bfrag[ct][ks], acc[ct], 0, 0, 0);
    }
#pragma unroll
    for (int j = 0; j < 4; j++) {
      int row = tb + wr * 16 + lg * 4 + j;
      bool ok = row < n;
      if (ok) {
#pragma unroll
        for (int ct = 0; ct < 4; ct++)
          xb[(size_t)row * 128 + ch * 64 + ct * 16 + lr] = f2bf(acc[ct][j]);
      }
      float psA = acc[0][j] * avs[0] + acc[1][j] * avs[1];
      float pdA = acc[0][j] * avd[0] + acc[1][j] * avd[1];
      float psB = acc[2][j] * avs[2] + acc[3][j] * avs[3];
      float pdB = acc[2][j] * avd[2] + acc[3][j] * avd[3];
#pragma unroll
      for (int m = 1; m <= 8; m <<= 1) {
        psA += __shfl_xor(psA, m); pdA += __shfl_xor(pdA, m);
        psB += __shfl_xor(psB, m); pdB += __shfl_xor(pdB, m);
      }
      if (lr == 0 && ok) {
        a_s[(size_t)row * 4 + ch * 2] = psA;
        a_s[(size_t)row * 4 + ch * 2 + 1] = psB;
        a_d[(size_t)row * 4 + ch * 2] = pdA;
        a_d[(size_t)row * 4 + ch * 2 + 1] = pdB;
      }
    }
  }
}

// -------- per-dst softmax: shfl-light online reduction + 2x-unrolled packed bf16 gather --------
// edge record: rec[j*16 + l*4 + hh] = bf16 logit; src int at rec[j*16+12].
__global__ void k_agg(const unsigned short* __restrict__ xb, const float* __restrict__ a_s,
                      const float* __restrict__ a_d, const unsigned short* __restrict__ rec,
                      const float* __restrict__ aeL,
                      const int* __restrict__ rowptr, const float* __restrict__ bias,
                      unsigned short* __restrict__ hbout, int n, int E, int l) {
  int wid = threadIdx.x >> 6;
  int v = blockIdx.x * 4 + wid;
  if (v >= n) return;
  int lane = threadIdx.x & 63;
  int el = lane >> 2;
  int hh = lane & 3;
  float ad_own = a_d[(size_t)v * 4 + hh];
  float as_own = a_s[(size_t)v * 4 + hh];
  float aeL_own = aeL[((size_t)l * n + v) * 4 + hh];
  float m_own = leaky02(as_own + ad_own + aeL_own);
  float s_own = 1.f;  // self contributes exp(0)
  int c2 = lane * 2;
  int headO = lane >> 4;
  const char* xB = (const char*)xb;
  uint32 coff = (uint32)c2 * 2u;
  uint32 wv = *(const uint32*)(xB + ((uint32)v << 8) + coff);
  float a0 = bflo(wv);
  float a1 = bfhi(wv);
  int beg = rowptr[v], end = rowptr[v + 1];
  for (int cb = beg; cb < end; cb += 16) {
    int ne = end - cb;
    if (ne > 16) ne = 16;
    float logit = -1e30f;
    int srcE = 0;
    if (el < ne) {
      int j = cb + el;
      const unsigned short* rp = rec + (size_t)j * 16;
      srcE = *(const int*)(rp + 12);
      float aev = bf2f((uint32)rp[l * 4 + hh]);
      float asrc = a_s[(size_t)srcE * 4 + hh];
      logit = leaky02(asrc + ad_own + aev);
    }
    float cm = logit;
    cm = fmaxf(cm, __shfl_xor(cm, 4));
    cm = fmaxf(cm, __shfl_xor(cm, 8));
    cm = fmaxf(cm, __shfl_xor(cm, 16));
    cm = fmaxf(cm, __shfl_xor(cm, 32));
    float mn_own = fmaxf(m_own, cm);
    float p = (el < ne) ? __expf(logit - mn_own) : 0.f;
    float ps = p;
    ps += __shfl_xor(ps, 4);
    ps += __shfl_xor(ps, 8);
    ps += __shfl_xor(ps, 16);
    ps += __shfl_xor(ps, 32);
    float c_own = __expf(m_own - mn_own);
    m_own = mn_own;
    s_own = s_own * c_own + ps;
    float cO = __shfl(c_own, headO);
    a0 *= cO;
    a1 *= cO;
    int e = 0;
    for (; e + 2 <= ne; e += 2) {
      int se0 = __builtin_amdgcn_readlane(srcE, e * 4);
      int se1 = __builtin_amdgcn_readlane(srcE, e * 4 + 4);
      float p0 = __shfl(p, e * 4 + headO);
      float p1 = __shfl(p, e * 4 + 4 + headO);
      uint32 x0 = *(const uint32*)(xB + ((uint32)se0 << 8) + coff);
      uint32 x1 = *(const uint32*)(xB + ((uint32)se1 << 8) + coff);
      a0 += p0 * bflo(x0) + p1 * bflo(x1);
      a1 += p0 * bfhi(x0) + p1 * bfhi(x1);
    }
    if (e < ne) {
      int se = __builtin_amdgcn_readlane(srcE, e * 4);
      float pC = __shfl(p, e * 4 + headO);
      uint32 xw = *(const uint32*)(xB + ((uint32)se << 8) + coff);
      a0 += pC * bflo(xw);
      a1 += pC * bfhi(xw);
    }
  }
  float sO = __shfl(s_own, headO);
  float r0 = fmaxf(a0 / sO + bias[l * HID + c2], 0.f);
  float r1 = fmaxf(a1 / sO + bias[l * HID + c2 + 1], 0.f);
  uint32 pk = (uint32)f2bf(r0) | ((uint32)f2bf(r1) << 16);
  *(uint32*)(hbout + (size_t)v * HID + c2) = pk;
}

// ---------------- pooling over bf16 h: batch sorted -> register accumulate ----------------
__global__ void k_pool(const unsigned short* __restrict__ hb, const int* __restrict__ batch,
                       float* __restrict__ g, int n) {
  int t = threadIdx.x;  // 128
  int per = (n + gridDim.x - 1) / gridDim.x;
  int start = blockIdx.x * per;
  int end = min(n, start + per);
  float acc = 0.f;
  int cur = -1;
  for (int v = start; v < end; v++) {
    int b = batch[v];
    if (b != cur) {
      if (cur >= 0) atomicAdd(&g[cur * 128 + t], acc);
      acc = 0.f;
      cur = b;
    }
    acc += bf2f((uint32)hb[(size_t)v * 128 + t]);
  }
  if (cur >= 0) atomicAdd(&g[cur * 128 + t], acc);
}

// ---------------- head MLP: one block per graph, LDS tree reduce ----------------
__global__ void k_head(const float* __restrict__ g, const float* __restrict__ Wr1,
                       const float* __restrict__ br1, const float* __restrict__ Wr2,
                       const float* __restrict__ br2, float* __restrict__ out, int G_) {
  __shared__ float gl[128];
  __shared__ float red[128];
  int i = blockIdx.x;
  int t = threadIdx.x;  // 128
  gl[t] = g[i * 128 + t];
  __syncthreads();
  float acc = br1[t];
  for (int k = 0; k < 128; k++) acc += gl[k] * Wr1[k * 128 + t];
  float hv = fmaxf(acc, 0.f);
  red[t] = hv * Wr2[t];
  __syncthreads();
  for (int off = 64; off >= 1; off >>= 1) {
    if (t < off) red[t] += red[t + off];
    __syncthreads();
  }
  if (t == 0) out[i] = red[0] + br2[0];
}

extern "C" void kernel_launch(void* const* d_in, const int* in_sizes, int n_in,
                              void* d_out, int out_size, void* d_ws, size_t ws_size,
                              hipStream_t stream) {
  const float* node_numeric = (const float*)d_in[0];
  const int* node_cat0 = (const int*)d_in[1];
  const int* node_cat1 = (const int*)d_in[2];
  const float* edge_numeric = (const float*)d_in[3];
  const int* edge_cat0 = (const int*)d_in[4];
  const int* edge_cat1 = (const int*)d_in[5];
  const int* edge_index = (const int*)d_in[6];
  const int* batch = (const int*)d_in[7];
  const float* recipe = (const float*)d_in[8];
  const float* emb_node0 = (const float*)d_in[9];
  const float* emb_node1 = (const float*)d_in[10];
  const float* emb_edge0 = (const float*)d_in[11];
  const float* emb_edge1 = (const float*)d_in[12];
  const float* W_in = (const float*)d_in[13];
  const float* b_in = (const float*)d_in[14];
  const float* W_edge = (const float*)d_in[15];
  const float* b_edge = (const float*)d_in[16];
  const float* gat_lin = (const float*)d_in[17];
  const float* gat_lin_edge = (const float*)d_in[18];
  const float* att_src = (const float*)d_in[19];
  const float* att_dst = (const float*)d_in[20];
  const float* att_edge = (const float*)d_in[21];
  const float* gat_bias = (const float*)d_in[22];
  const float* W_r1 = (const float*)d_in[23];
  const float* b_r1 = (const float*)d_in[24];
  const float* W_r2 = (const float*)d_in[25];
  const float* b_r2 = (const float*)d_in[26];

  int N = in_sizes[0] / 8;
  int E = in_sizes[3] / 4;
  int Gn = in_sizes[8] / 16;
  const int* srcArr = edge_index;
  const int* dstArr = edge_index + E;

  char* ws = (char*)d_ws;
  size_t o = 0;
  auto alloc = [&](size_t b) {
    char* p = ws + o;
    o = (o + b + 255) & ~(size_t)255;
    return p;
  };
  unsigned short* hbf = (unsigned short*)alloc((size_t)N * 128 * 2);
  unsigned short* xbf = (unsigned short*)alloc((size_t)N * 128 * 2);
  unsigned short* rec = (unsigned short*)alloc((size_t)E * 16 * 2);  // 32B/edge records
  float* aeL = (float*)alloc((size_t)N * 12 * 4);   // layer-major [3][N][4]
  float* a_s = (float*)alloc((size_t)N * 4 * 4);
  float* a_d = (float*)alloc((size_t)N * 4 * 4);
  float* P = (float*)alloc(216 * 4);
  float* q = (float*)alloc(12 * 4);
  unsigned short* WbfT = (unsigned short*)alloc(3 * 128 * 128 * 2);
  int* cnt = (int*)alloc((size_t)N * 4);
  int* rowptr = (int*)alloc((size_t)(N + 1) * 4);
  int* cursor = (int*)alloc((size_t)N * 4);
  int* bsum = (int*)alloc(512 * 4);
  float* g = (float*)alloc((size_t)Gn * 128 * 4);
  (void)ws_size;

  (void)hipMemsetAsync(cnt, 0, (size_t)N * 4, stream);
  (void)hipMemsetAsync(g, 0, (size_t)Gn * 128 * 4, stream);

  int nbl = (N + 255) / 256;
  int ebl = (E + 255) / 256;

  k_enc<<<2048, 256, 0, stream>>>(node_numeric, node_cat0, node_cat1, batch, recipe,
                                  emb_node0, emb_node1, W_in, b_in, hbf, N);
  k_prep<<<3, 256, 0, stream>>>(gat_lin_edge, att_edge, W_edge, b_edge, P, q);
  k_wprep<<<192, 256, 0, stream>>>(gat_lin, WbfT);
  k_deg<<<ebl, 256, 0, stream>>>(dstArr, cnt, E);
  k_scan1<<<nbl, 256, 0, stream>>>(cnt, rowptr, bsum, N);
  k_scan2<<<1, 512, 0, stream>>>(bsum, nbl);
  k_scan3<<<nbl, 256, 0, stream>>>(rowptr, bsum, cursor, N, E);
  k_ae<<<ebl, 256, 0, stream>>>(edge_numeric, edge_cat0, edge_cat1, dstArr, srcArr,
                                emb_edge0, emb_edge1, P, q, cursor, rec, E);
  k_loopmean<<<nbl, 256, 0, stream>>>(rec, rowptr, aeL, N, E);

  for (int l = 0; l < 3; l++) {
    k_x<<<1024, 512, 0, stream>>>(hbf, WbfT + l * 16384, att_src + l * 128,
                                  att_dst + l * 128, xbf, a_s, a_d, N);
    k_agg<<<(N + 3) / 4, 256, 0, stream>>>(xbf, a_s, a_d, rec, aeL, rowptr,
                                           gat_bias, hbf, N, E, l);
  }
  k_pool<<<1024, 128, 0, stream>>>(hbf, batch, g, N);
  k_head<<<Gn, 128, 0, stream>>>(g, W_r1, b_r1, W_r2, b_r2, (float*)d_out, Gn);
}

// Round 20
// 383.994 us; speedup vs baseline: 1.2088x; 1.0914x over previous
//
#include <hip/hip_runtime.h>
#include <math.h>

#define HID 128

typedef float f32x4 __attribute__((ext_vector_type(4)));
typedef short bf16x8 __attribute__((ext_vector_type(8)));
typedef unsigned int uint32;

__device__ __forceinline__ float leaky02(float z) { return z >= 0.f ? z : 0.2f * z; }
__device__ __forceinline__ unsigned short f2bf(float f) {
  uint32 u = __float_as_uint(f);
  u = (u + 0x7fff + ((u >> 16) & 1)) >> 16;  // RNE
  return (unsigned short)u;
}
__device__ __forceinline__ float bf2f(uint32 us) { return __uint_as_float(us << 16); }
__device__ __forceinline__ float bflo(uint32 w) { return __uint_as_float(w << 16); }
__device__ __forceinline__ float bfhi(uint32 w) { return __uint_as_float(w & 0xffff0000u); }

// ---------------- node encoder: h_bf = relu(concat(feat) @ W_in + b_in) ----------------
__global__ void k_enc(const float* __restrict__ nodenum, const int* __restrict__ c0,
                      const int* __restrict__ c1, const int* __restrict__ batch,
                      const float* __restrict__ recipe,
                      const float* __restrict__ e0, const float* __restrict__ e1,
                      const float* __restrict__ Win, const float* __restrict__ bin,
                      unsigned short* __restrict__ hb, int n) {
  __shared__ float f[8][40];
  __shared__ int idx[8][3];
  int t = threadIdx.x;  // 256
  int col = t & 127;
  int half = t >> 7;
  float w[40];
#pragma unroll
  for (int k = 0; k < 38; k++) w[k] = Win[k * 128 + col];
  w[38] = 0.f;
  w[39] = 0.f;
  float bias = bin[col];
  int ntiles = (n + 7) / 8;
  for (int tile = blockIdx.x; tile < ntiles; tile += gridDim.x) {
    int base = tile * 8;
    if (t < 64) {
      int r = t >> 3, k = t & 7;
      int v = base + r;
      f[r][k] = (v < n) ? nodenum[(size_t)v * 8 + k] : 0.f;
    } else if (t < 88) {
      int j = t - 64;
      int r = j / 3, which = j - r * 3;
      int v = base + r;
      int val = 0;
      if (v < n) val = (which == 0) ? c0[v] : ((which == 1) ? c1[v] : batch[v]);
      idx[r][which] = val;
    } else if (t >= 240) {
      int r = t - 240;
      if (r < 8) { f[r][38] = 0.f; f[r][39] = 0.f; }
    }
    __syncthreads();
    if (t < 240) {
      int r = t / 30, k = t - r * 30;
      float val;
      if (k < 6) val = e0[idx[r][0] * 6 + k];
      else if (k < 14) val = e1[idx[r][1] * 8 + (k - 6)];
      else val = recipe[idx[r][2] * 16 + (k - 14)];
      f[r][8 + k] = val;
    }
    __syncthreads();
#pragma unroll
    for (int rr = 0; rr < 4; rr++) {
      int r = half * 4 + rr;
      int v = base + r;
      float acc = bias;
#pragma unroll
      for (int k4 = 0; k4 < 10; k4++) {
        float4 fv = *(const float4*)(&f[r][k4 * 4]);
        acc += fv.x * w[k4 * 4] + fv.y * w[k4 * 4 + 1] + fv.z * w[k4 * 4 + 2] +
               fv.w * w[k4 * 4 + 3];
      }
      if (v < n) hb[(size_t)v * 128 + col] = f2bf(fmaxf(acc, 0.f));
    }
    __syncthreads();
  }
}

// ---- parallel precompute P_l (18x4), q_l (4); one block per layer ----
__global__ void k_prep(const float* __restrict__ gle, const float* __restrict__ atte,
                       const float* __restrict__ We, const float* __restrict__ be,
                       float* __restrict__ P, float* __restrict__ q) {
  __shared__ float M[512];  // [k][hh]
  int l = blockIdx.x;
  int t = threadIdx.x;  // 256
#pragma unroll
  for (int i = 0; i < 2; i++) {
    int idx = t + i * 256;
    int k = idx >> 2, hh = idx & 3;
    float acc = 0.f;
    for (int c = 0; c < 32; c++)
      acc += gle[l * 16384 + k * 128 + hh * 32 + c] * atte[l * 128 + hh * 32 + c];
    M[k * 4 + hh] = acc;
  }
  __syncthreads();
  if (t < 72) {
    int j = t >> 2, hh = t & 3;
    float acc = 0.f;
    for (int k = 0; k < 128; k++) acc += We[j * 128 + k] * M[k * 4 + hh];
    P[(l * 18 + j) * 4 + hh] = acc;
  } else if (t < 76) {
    int hh = t - 72;
    float acc = 0.f;
    for (int k = 0; k < 128; k++) acc += be[k] * M[k * 4 + hh];
    q[l * 4 + hh] = acc;
  }
}

// ---- precompute WbfT[l][col][k] = bf16(gat_lin[l][k][col]) ----
__global__ void k_wprep(const float* __restrict__ glin, unsigned short* __restrict__ WbfT) {
  int idx = blockIdx.x * 256 + threadIdx.x;
  if (idx >= 3 * 128 * 128) return;
  int l = idx >> 14;
  int rem = idx & 16383;
  int col = rem >> 7;
  int k = rem & 127;
  WbfT[idx] = f2bf(glin[(l << 14) + k * 128 + col]);
}

// ---------------- degree histogram ----------------
__global__ void k_deg(const int* __restrict__ dst, int* __restrict__ cnt, int E) {
  int i = blockIdx.x * 256 + threadIdx.x;
  if (i < E) atomicAdd(&cnt[dst[i]], 1);
}

// ------- per-edge record (32B): 12 bf16 logits (3 layers x 4 heads) + src int + pad -------
__global__ void k_ae(const float* __restrict__ enum_, const int* __restrict__ ec0,
                     const int* __restrict__ ec1, const int* __restrict__ dst,
                     const int* __restrict__ srcarr,
                     const float* __restrict__ ee0, const float* __restrict__ ee1,
                     const float* __restrict__ P, const float* __restrict__ q,
                     int* __restrict__ cursor, unsigned short* __restrict__ rec,
                     int E) {
  __shared__ float Ps[216];
  __shared__ float qs[12];
  int t = threadIdx.x;
  for (int i = t; i < 216; i += 256) Ps[i] = P[i];
  if (t < 12) qs[t] = q[t];
  __syncthreads();
  int i = blockIdx.x * 256 + t;
  if (i >= E) return;
  float raw[18];
  float4 nm = *(const float4*)(enum_ + (size_t)i * 4);
  raw[0] = nm.x; raw[1] = nm.y; raw[2] = nm.z; raw[3] = nm.w;
  int a0 = ec0[i], a1 = ec1[i];
  float4 eb0 = *(const float4*)(ee0 + a0 * 4);
  raw[4] = eb0.x; raw[5] = eb0.y; raw[6] = eb0.z; raw[7] = eb0.w;
#pragma unroll
  for (int j = 0; j < 10; j++) raw[8 + j] = ee1[a1 * 10 + j];
  int d = dst[i];
  int pos = atomicAdd(&cursor[d], 1);
  uint32 wbuf[8];
#pragma unroll
  for (int l = 0; l < 3; l++) {
    float o[4];
#pragma unroll
    for (int hh = 0; hh < 4; hh++) {
      float acc = qs[l * 4 + hh];
#pragma unroll
      for (int j = 0; j < 18; j++) acc += raw[j] * Ps[(l * 18 + j) * 4 + hh];
      o[hh] = acc;
    }
    wbuf[l * 2] = (uint32)f2bf(o[0]) | ((uint32)f2bf(o[1]) << 16);
    wbuf[l * 2 + 1] = (uint32)f2bf(o[2]) | ((uint32)f2bf(o[3]) << 16);
  }
  wbuf[6] = (uint32)srcarr[i];
  wbuf[7] = 0;
  uint4* dp = (uint4*)(rec + (size_t)pos * 16);
  dp[0] = make_uint4(wbuf[0], wbuf[1], wbuf[2], wbuf[3]);
  dp[1] = make_uint4(wbuf[4], wbuf[5], wbuf[6], wbuf[7]);
}

// ---- node-parallel self-loop means from records; aeL layer-major [l][v][4] f32 ----
__global__ void k_loopmean(const unsigned short* __restrict__ rec,
                           const int* __restrict__ rowptr,
                           float* __restrict__ aeL, int n, int E) {
  int v = blockIdx.x * 256 + threadIdx.x;
  if (v >= n) return;
  int beg = rowptr[v], end = rowptr[v + 1];
  float s[12];
#pragma unroll
  for (int m = 0; m < 12; m++) s[m] = 0.f;
  for (int j = beg; j < end; j++) {
    const uint4* rp = (const uint4*)(rec + (size_t)j * 16);
    uint4 r0 = rp[0];
    uint32 w4 = ((const uint32*)&rp[1])[0];
    uint32 w5 = ((const uint32*)&rp[1])[1];
    s[0] += bflo(r0.x); s[1] += bfhi(r0.x);
    s[2] += bflo(r0.y); s[3] += bfhi(r0.y);
    s[4] += bflo(r0.z); s[5] += bfhi(r0.z);
    s[6] += bflo(r0.w); s[7] += bfhi(r0.w);
    s[8] += bflo(w4);   s[9] += bfhi(w4);
    s[10] += bflo(w5);  s[11] += bfhi(w5);
  }
  float inv = (end > beg) ? 1.f / (float)(end - beg) : 0.f;
#pragma unroll
  for (int l = 0; l < 3; l++)
    *(float4*)(aeL + ((size_t)l * n + v) * 4) =
        make_float4(s[l * 4] * inv, s[l * 4 + 1] * inv, s[l * 4 + 2] * inv,
                    s[l * 4 + 3] * inv);
}

// ---------------- CSR build: exclusive scan of cnt -> rowptr (cursor = copy) ----------------
__global__ void k_scan1(const int* __restrict__ cnt, int* __restrict__ excl,
                        int* __restrict__ bsum, int n) {
  __shared__ int sh[256];
  int t = threadIdx.x;
  int i = blockIdx.x * 256 + t;
  int v = (i < n) ? cnt[i] : 0;
  sh[t] = v;
  __syncthreads();
  for (int off = 1; off < 256; off <<= 1) {
    int add = (t >= off) ? sh[t - off] : 0;
    __syncthreads();
    sh[t] += add;
    __syncthreads();
  }
  if (i < n) excl[i] = sh[t] - v;
  if (t == 255) bsum[blockIdx.x] = sh[255];
}

__global__ void k_scan2(int* __restrict__ bsum, int nb) {
  __shared__ int sh[512];
  int t = threadIdx.x;
  int v = (t < nb) ? bsum[t] : 0;
  sh[t] = v;
  __syncthreads();
  for (int off = 1; off < 512; off <<= 1) {
    int add = (t >= off) ? sh[t - off] : 0;
    __syncthreads();
    sh[t] += add;
    __syncthreads();
  }
  if (t < nb) bsum[t] = sh[t] - v;
}

__global__ void k_scan3(int* __restrict__ rowptr, const int* __restrict__ boff,
                        int* __restrict__ cursor, int n, int E) {
  int i = blockIdx.x * 256 + threadIdx.x;
  if (i < n) {
    int val = rowptr[i] + boff[i >> 8];
    rowptr[i] = val;
    cursor[i] = val;
  }
  if (i == 0) rowptr[n] = E;
}

// ------- x = h @ gat_lin[l] via bf16 MFMA; LDS-staged h; fused a_s/a_d epilogue -------
__global__ void __launch_bounds__(512, 4)
k_x(const unsigned short* __restrict__ hb, const unsigned short* __restrict__ WbfT,
    const float* __restrict__ att_s, const float* __restrict__ att_d,
    unsigned short* __restrict__ xb, float* __restrict__ a_s,
    float* __restrict__ a_d, int n) {
  __shared__ unsigned short hs[64 * 128];
  int t = threadIdx.x;  // 512
  int w = t >> 6, l = t & 63;
  int ch = w >> 2, wr = w & 3;
  int lr = l & 15, lg = l >> 4;
  bf16x8 bfrag[4][4];
#pragma unroll
  for (int ct = 0; ct < 4; ct++) {
#pragma unroll
    for (int ks = 0; ks < 4; ks++) {
      int col = ch * 64 + ct * 16 + lr;
      int k0 = ks * 32 + lg * 8;
      bfrag[ct][ks] = *(const bf16x8*)(WbfT + col * 128 + k0);
    }
  }
  float avs[4], avd[4];
#pragma unroll
  for (int ct = 0; ct < 4; ct++) {
    avs[ct] = att_s[ch * 64 + ct * 16 + lr];
    avd[ct] = att_d[ch * 64 + ct * 16 + lr];
  }
  for (int tb = blockIdx.x * 64; tb < n; tb += gridDim.x * 64) {
    __syncthreads();
#pragma unroll
    for (int i = 0; i < 2; i++) {
      int idx = t + i * 512;
      int r = idx >> 4, c = idx & 15;
      uint4 vv = make_uint4(0, 0, 0, 0);
      if (tb + r < n) vv = *(const uint4*)(hb + (size_t)(tb + r) * 128 + c * 8);
      *(uint4*)(&hs[r * 128 + ((c ^ (r & 7)) * 8)]) = vv;
    }
    __syncthreads();
    f32x4 acc[4];
#pragma unroll
    for (int ct = 0; ct < 4; ct++) acc[ct] = (f32x4){0.f, 0.f, 0.f, 0.f};
#pragma unroll
    for (int ks = 0; ks < 4; ks++) {
      int r = wr * 16 + lr;
      int c = ks * 4 + lg;
      bf16x8 a = *(const bf16x8*)(&hs[r * 128 + ((c ^ (r & 7)) * 8)]);
#pragma unroll
      for (int ct = 0; ct < 4; ct++)
        acc[ct] = __builtin_amdgcn_mfma_f32_16x16x32_bf16(a, bfrag[ct][ks], acc[ct], 0, 0, 0);
    }
#pragma unroll
    for (int j = 0; j < 4; j++) {
      int row = tb + wr * 16 + lg * 4 + j;
      bool ok = row < n;
      if (ok) {
#pragma unroll
        for (int ct = 0; ct < 4; ct++)
          xb[(size_t)row * 128 + ch * 64 + ct * 16 + lr] = f2bf(acc[ct][j]);
      }
      float psA = acc[0][j] * avs[0] + acc[1][j] * avs[1];
      float pdA = acc[0][j] * avd[0] + acc[1][j] * avd[1];
      float psB = acc[2][j] * avs[2] + acc[3][j] * avs[3];
      float pdB = acc[2][j] * avd[2] + acc[3][j] * avd[3];
#pragma unroll
      for (int m = 1; m <= 8; m <<= 1) {
        psA += __shfl_xor(psA, m); pdA += __shfl_xor(pdA, m);
        psB += __shfl_xor(psB, m); pdB += __shfl_xor(pdB, m);
      }
      if (lr == 0 && ok) {
        a_s[(size_t)row * 4 + ch * 2] = psA;
        a_s[(size_t)row * 4 + ch * 2 + 1] = psB;
        a_d[(size_t)row * 4 + ch * 2] = pdA;
        a_d[(size_t)row * 4 + ch * 2 + 1] = pdB;
      }
    }
  }
}

// -------- per-dst softmax: TWO nodes per wave (32 lanes/node, 4 cols/lane as uint2) --------
// half = lane>>5 selects node; within half: slot el=(lane&31)>>2 (8 slots), head hh=lane&3.
// Col phase: lane owns cols [hl*4, hl*4+4), head hd = hl>>3. Butterflies xor 4/8/16 stay in-half.
__global__ void k_agg(const unsigned short* __restrict__ xb, const float* __restrict__ a_s,
                      const float* __restrict__ a_d, const unsigned short* __restrict__ rec,
                      const float* __restrict__ aeL,
                      const int* __restrict__ rowptr, const float* __restrict__ bias,
                      unsigned short* __restrict__ hbout, int n, int E, int l) {
  int wid = threadIdx.x >> 6;
  int lane = threadIdx.x & 63;
  int half = lane >> 5;
  int hl = lane & 31;
  int v = blockIdx.x * 8 + wid * 2 + half;
  bool act = v < n;
  int vL = act ? v : 0;
  int el = hl >> 2;
  int hh = lane & 3;
  int hd = hl >> 3;  // head of owned cols
  float ad_own = act ? a_d[(size_t)vL * 4 + hh] : 0.f;
  float as_own = act ? a_s[(size_t)vL * 4 + hh] : 0.f;
  float aeL_own = act ? aeL[((size_t)l * n + vL) * 4 + hh] : 0.f;
  float m_own = leaky02(as_own + ad_own + aeL_own);
  float s_own = 1.f;  // self contributes exp(0)
  const char* xB = (const char*)xb;
  uint32 coff = (uint32)hl * 8u;
  uint2 xw0 = *(const uint2*)(xB + ((uint32)vL << 8) + coff);
  float a0 = bflo(xw0.x), a1 = bfhi(xw0.x), a2 = bflo(xw0.y), a3 = bfhi(xw0.y);
  int beg = act ? rowptr[vL] : 0;
  int end = act ? rowptr[vL + 1] : 0;
  int hbase = lane & 32;  // 0 or 32: base lane of my half
  for (int cb = beg; cb < end; cb += 8) {
    int ne = end - cb;
    if (ne > 8) ne = 8;
    float logit = -1e30f;
    int srcE = 0;
    if (el < ne) {
      int j = cb + el;
      const unsigned short* rp = rec + (size_t)j * 16;
      srcE = *(const int*)(rp + 12);
      float aev = bf2f((uint32)rp[l * 4 + hh]);
      float asrc = a_s[(size_t)srcE * 4 + hh];
      logit = leaky02(asrc + ad_own + aev);
    }
    float cm = logit;
    cm = fmaxf(cm, __shfl_xor(cm, 4));
    cm = fmaxf(cm, __shfl_xor(cm, 8));
    cm = fmaxf(cm, __shfl_xor(cm, 16));
    float mn_own = fmaxf(m_own, cm);
    float p = (el < ne) ? __expf(logit - mn_own) : 0.f;
    float ps = p;
    ps += __shfl_xor(ps, 4);
    ps += __shfl_xor(ps, 8);
    ps += __shfl_xor(ps, 16);
    float c_own = __expf(m_own - mn_own);
    m_own = mn_own;
    s_own = s_own * c_own + ps;
    float cO = __shfl(c_own, hbase | hd);
    a0 *= cO; a1 *= cO; a2 *= cO; a3 *= cO;
    int e = 0;
    for (; e + 2 <= ne; e += 2) {
      int se0 = __shfl(srcE, hbase | (e * 4));
      int se1 = __shfl(srcE, hbase | (e * 4 + 4));
      float p0 = __shfl(p, hbase | (e * 4) | hd);
      float p1 = __shfl(p, hbase | (e * 4 + 4) | hd);
      uint2 x0 = *(const uint2*)(xB + ((uint32)se0 << 8) + coff);
      uint2 x1 = *(const uint2*)(xB + ((uint32)se1 << 8) + coff);
      a0 += p0 * bflo(x0.x) + p1 * bflo(x1.x);
      a1 += p0 * bfhi(x0.x) + p1 * bfhi(x1.x);
      a2 += p0 * bflo(x0.y) + p1 * bflo(x1.y);
      a3 += p0 * bfhi(x0.y) + p1 * bfhi(x1.y);
    }
    if (e < ne) {
      int se = __shfl(srcE, hbase | (e * 4));
      float pC = __shfl(p, hbase | (e * 4) | hd);
      uint2 xw = *(const uint2*)(xB + ((uint32)se << 8) + coff);
      a0 += pC * bflo(xw.x);
      a1 += pC * bfhi(xw.x);
      a2 += pC * bflo(xw.y);
      a3 += pC * bfhi(xw.y);
    }
  }
  float sO = __shfl(s_own, hbase | hd);
  float4 bv = *(const float4*)(bias + l * HID + hl * 4);
  float r0 = fmaxf(a0 / sO + bv.x, 0.f);
  float r1 = fmaxf(a1 / sO + bv.y, 0.f);
  float r2 = fmaxf(a2 / sO + bv.z, 0.f);
  float r3 = fmaxf(a3 / sO + bv.w, 0.f);
  if (act) {
    uint2 pk;
    pk.x = (uint32)f2bf(r0) | ((uint32)f2bf(r1) << 16);
    pk.y = (uint32)f2bf(r2) | ((uint32)f2bf(r3) << 16);
    *(uint2*)(hbout + (size_t)vL * HID + hl * 4) = pk;
  }
}

// ---------------- pooling over bf16 h: batch sorted -> register accumulate ----------------
__global__ void k_pool(const unsigned short* __restrict__ hb, const int* __restrict__ batch,
                       float* __restrict__ g, int n) {
  int t = threadIdx.x;  // 128
  int per = (n + gridDim.x - 1) / gridDim.x;
  int start = blockIdx.x * per;
  int end = min(n, start + per);
  float acc = 0.f;
  int cur = -1;
  for (int v = start; v < end; v++) {
    int b = batch[v];
    if (b != cur) {
      if (cur >= 0) atomicAdd(&g[cur * 128 + t], acc);
      acc = 0.f;
      cur = b;
    }
    acc += bf2f((uint32)hb[(size_t)v * 128 + t]);
  }
  if (cur >= 0) atomicAdd(&g[cur * 128 + t], acc);
}

// ---------------- head MLP: one block per graph, LDS tree reduce ----------------
__global__ void k_head(const float* __restrict__ g, const float* __restrict__ Wr1,
                       const float* __restrict__ br1, const float* __restrict__ Wr2,
                       const float* __restrict__ br2, float* __restrict__ out, int G_) {
  __shared__ float gl[128];
  __shared__ float red[128];
  int i = blockIdx.x;
  int t = threadIdx.x;  // 128
  gl[t] = g[i * 128 + t];
  __syncthreads();
  float acc = br1[t];
  for (int k = 0; k < 128; k++) acc += gl[k] * Wr1[k * 128 + t];
  float hv = fmaxf(acc, 0.f);
  red[t] = hv * Wr2[t];
  __syncthreads();
  for (int off = 64; off >= 1; off >>= 1) {
    if (t < off) red[t] += red[t + off];
    __syncthreads();
  }
  if (t == 0) out[i] = red[0] + br2[0];
}

extern "C" void kernel_launch(void* const* d_in, const int* in_sizes, int n_in,
                              void* d_out, int out_size, void* d_ws, size_t ws_size,
                              hipStream_t stream) {
  const float* node_numeric = (const float*)d_in[0];
  const int* node_cat0 = (const int*)d_in[1];
  const int* node_cat1 = (const int*)d_in[2];
  const float* edge_numeric = (const float*)d_in[3];
  const int* edge_cat0 = (const int*)d_in[4];
  const int* edge_cat1 = (const int*)d_in[5];
  const int* edge_index = (const int*)d_in[6];
  const int* batch = (const int*)d_in[7];
  const float* recipe = (const float*)d_in[8];
  const float* emb_node0 = (const float*)d_in[9];
  const float* emb_node1 = (const float*)d_in[10];
  const float* emb_edge0 = (const float*)d_in[11];
  const float* emb_edge1 = (const float*)d_in[12];
  const float* W_in = (const float*)d_in[13];
  const float* b_in = (const float*)d_in[14];
  const float* W_edge = (const float*)d_in[15];
  const float* b_edge = (const float*)d_in[16];
  const float* gat_lin = (const float*)d_in[17];
  const float* gat_lin_edge = (const float*)d_in[18];
  const float* att_src = (const float*)d_in[19];
  const float* att_dst = (const float*)d_in[20];
  const float* att_edge = (const float*)d_in[21];
  const float* gat_bias = (const float*)d_in[22];
  const float* W_r1 = (const float*)d_in[23];
  const float* b_r1 = (const float*)d_in[24];
  const float* W_r2 = (const float*)d_in[25];
  const float* b_r2 = (const float*)d_in[26];

  int N = in_sizes[0] / 8;
  int E = in_sizes[3] / 4;
  int Gn = in_sizes[8] / 16;
  const int* srcArr = edge_index;
  const int* dstArr = edge_index + E;

  char* ws = (char*)d_ws;
  size_t o = 0;
  auto alloc = [&](size_t b) {
    char* p = ws + o;
    o = (o + b + 255) & ~(size_t)255;
    return p;
  };
  unsigned short* hbf = (unsigned short*)alloc((size_t)N * 128 * 2);
  unsigned short* xbf = (unsigned short*)alloc((size_t)N * 128 * 2);
  unsigned short* rec = (unsigned short*)alloc((size_t)E * 16 * 2);  // 32B/edge records
  float* aeL = (float*)alloc((size_t)N * 12 * 4);   // layer-major [3][N][4]
  float* a_s = (float*)alloc((size_t)N * 4 * 4);
  float* a_d = (float*)alloc((size_t)N * 4 * 4);
  float* P = (float*)alloc(216 * 4);
  float* q = (float*)alloc(12 * 4);
  unsigned short* WbfT = (unsigned short*)alloc(3 * 128 * 128 * 2);
  int* cnt = (int*)alloc((size_t)N * 4);
  int* rowptr = (int*)alloc((size_t)(N + 1) * 4);
  int* cursor = (int*)alloc((size_t)N * 4);
  int* bsum = (int*)alloc(512 * 4);
  float* g = (float*)alloc((size_t)Gn * 128 * 4);
  (void)ws_size;

  (void)hipMemsetAsync(cnt, 0, (size_t)N * 4, stream);
  (void)hipMemsetAsync(g, 0, (size_t)Gn * 128 * 4, stream);

  int nbl = (N + 255) / 256;
  int ebl = (E + 255) / 256;

  k_enc<<<2048, 256, 0, stream>>>(node_numeric, node_cat0, node_cat1, batch, recipe,
                                  emb_node0, emb_node1, W_in, b_in, hbf, N);
  k_prep<<<3, 256, 0, stream>>>(gat_lin_edge, att_edge, W_edge, b_edge, P, q);
  k_wprep<<<192, 256, 0, stream>>>(gat_lin, WbfT);
  k_deg<<<ebl, 256, 0, stream>>>(dstArr, cnt, E);
  k_scan1<<<nbl, 256, 0, stream>>>(cnt, rowptr, bsum, N);
  k_scan2<<<1, 512, 0, stream>>>(bsum, nbl);
  k_scan3<<<nbl, 256, 0, stream>>>(rowptr, bsum, cursor, N, E);
  k_ae<<<ebl, 256, 0, stream>>>(edge_numeric, edge_cat0, edge_cat1, dstArr, srcArr,
                                emb_edge0, emb_edge1, P, q, cursor, rec, E);
  k_loopmean<<<nbl, 256, 0, stream>>>(rec, rowptr, aeL, N, E);

  for (int l = 0; l < 3; l++) {
    k_x<<<1024, 512, 0, stream>>>(hbf, WbfT + l * 16384, att_src + l * 128,
                                  att_dst + l * 128, xbf, a_s, a_d, N);
    k_agg<<<(N + 7) / 8, 256, 0, stream>>>(xbf, a_s, a_d, rec, aeL, rowptr,
                                           gat_bias, hbf, N, E, l);
  }
  k_pool<<<1024, 128, 0, stream>>>(hbf, batch, g, N);
  k_head<<<Gn, 128, 0, stream>>>(g, W_r1, b_r1, W_r2, b_r2, (float*)d_out, Gn);
}